// Round 1
// baseline (34.882 us; speedup 1.0000x reference)
//
#include <hip/hip_runtime.h>

// ---------------------------------------------------------------------------
// TimeLSTMCell fused kernel for MI355X (gfx950) — round 3
// B=4096, D=256, U=512; out = concat(h, c_m) fp32
//
// prep kernel: converts x,h0 -> bf16 and kernel,rk -> transposed bf16, all
//   written as 128x64 (A) / {160,96}x64 (B) tiles with the LDS XOR-swizzle
//   PRE-BAKED into the tile layout, so the main kernel stages with linear
//   global_load_lds (wave-uniform dest + lane*16) and reads with the swizzle.
// main kernel: 128x32 output tile, 4 waves, BK=64, double-buffered LDS,
//   2-phase pipeline (STAGE next || COMPUTE cur || barrier), 12 K-steps
//   (4 for x@kernel K=256, 8 for h0@rk K=512), fused fp32 epilogue.
//
// ROUND 3 CHANGE: XCD-aware block remap. Grid flattened to 1-D (512 blocks,
//   all co-resident at 2 blocks/CU). Default round-robin id%8 put all 32 rb
//   bands on every XCD -> 6 MB A working set per 4 MB L2 -> the ~188 MB of
//   staging re-reads fell to L3/HBM. New mapping gives XCD k an 8x8 (nb,rb)
//   quadrant: 1.5 MB A + 1.4 MB B = 2.9 MB < 4 MB L2, so tile re-reads are
//   L2-resident. Bijective (512 %% 8 == 0). No other changes.
// ---------------------------------------------------------------------------

typedef __attribute__((ext_vector_type(8))) short short8_t;   // 8 bf16
typedef __attribute__((ext_vector_type(4))) float f32x4_t;
typedef unsigned int u32;

#define B_N 4096
#define D_K 256
#define U_N 512

__device__ __forceinline__ unsigned short f2bf(float f) {
    unsigned int x = __float_as_uint(f);
    unsigned int r = x + 0x7fffu + ((x >> 16) & 1u);   // RNE
    return (unsigned short)(r >> 16);
}

__device__ __forceinline__ float sigf(float z) {
    return 1.0f / (1.0f + __expf(-z));
}

__device__ __forceinline__ void gl16(const unsigned short* g, unsigned short* l) {
    __builtin_amdgcn_global_load_lds(
        (const __attribute__((address_space(1))) u32*)g,
        (__attribute__((address_space(3))) u32*)l, 16, 0, 0);
}

// swizzled element offset of (row r, k-chunk kc) inside a tile with 8 chunks/row
#define SWZ(r, kc) ((((r) * 8) + ((kc) ^ ((r) & 7))) * 8)

// ---------------------------------------------------------------------------
// prepass: one kernel, 4 segments by flat chunk id (16B bf16 chunk each)
//   x  : 131072 chunks -> tiles (rb 0..31, kb 0..3)  of 128x64
//   h0 : 262144 chunks -> tiles (rb 0..31, kb 0..7)  of 128x64
//   ker:  81920 chunks -> tiles (nb 0..15, kb 0..3)  of 160x64 (transposed)
//   rk :  98304 chunks -> tiles (nb 0..15, kb 0..7)  of  96x64 (transposed)
// total 573440 chunks = 2240 blocks x 256
// ---------------------------------------------------------------------------
__global__ __launch_bounds__(256) void prep(
    const float* __restrict__ x, const float* __restrict__ h0,
    const float* __restrict__ kern, const float* __restrict__ rk,
    unsigned short* __restrict__ xs, unsigned short* __restrict__ hs,
    unsigned short* __restrict__ ksw, unsigned short* __restrict__ rsw)
{
    const int c = blockIdx.x * 256 + threadIdx.x;
    if (c < 131072) {                       // ---- x ----
        const int t = c >> 10, q = c & 1023;
        const int row = q >> 3, kc = q & 7;
        const int rb = t >> 2, kb = t & 3;
        const float* s = x + (size_t)(rb * 128 + row) * D_K + kb * 64 + kc * 8;
        short8_t o;
#pragma unroll
        for (int j = 0; j < 8; ++j) o[j] = (short)f2bf(s[j]);
        *reinterpret_cast<short8_t*>(xs + (size_t)t * 8192 + SWZ(row, kc)) = o;
    } else if (c < 393216) {                // ---- h0 ----
        const int c2 = c - 131072;
        const int t = c2 >> 10, q = c2 & 1023;
        const int row = q >> 3, kc = q & 7;
        const int rb = t >> 3, kb = t & 7;
        const float* s = h0 + (size_t)(rb * 128 + row) * U_N + kb * 64 + kc * 8;
        short8_t o;
#pragma unroll
        for (int j = 0; j < 8; ++j) o[j] = (short)f2bf(s[j]);
        *reinterpret_cast<short8_t*>(hs + (size_t)t * 8192 + SWZ(row, kc)) = o;
    } else if (c < 475136) {                // ---- kernel (transpose) ----
        const int c2 = c - 393216;
        const int t = c2 / 1280, q = c2 - t * 1280;
        const int kc = q / 160, r = q - kc * 160;     // r = mat*32 + cc
        const int nb = t >> 2, kb = t & 3;
        const int col = (r >> 5) * U_N + nb * 32 + (r & 31);
        short8_t o;
#pragma unroll
        for (int j = 0; j < 8; ++j)
            o[j] = (short)f2bf(kern[(size_t)(kb * 64 + kc * 8 + j) * 2560 + col]);
        *reinterpret_cast<short8_t*>(ksw + (size_t)t * 10240 + SWZ(r, kc)) = o;
    } else {                                // ---- rk (transpose) ----
        const int c2 = c - 475136;
        const int t = c2 / 768, q = c2 - t * 768;
        const int kc = q / 96, r = q - kc * 96;       // r = mat*32 + cc
        const int nb = t >> 3, kb = t & 7;
        const int col = (r >> 5) * U_N + nb * 32 + (r & 31);
        short8_t o;
#pragma unroll
        for (int j = 0; j < 8; ++j)
            o[j] = (short)f2bf(rk[(size_t)(kb * 64 + kc * 8 + j) * 1536 + col]);
        *reinterpret_cast<short8_t*>(rsw + (size_t)t * 6144 + SWZ(r, kc)) = o;
    }
}

// ---------------------------------------------------------------------------
// main fused kernel
// grid 512 (1-D, 2 blocks/CU), 256 threads (4 waves)
// XCD-aware remap: xcd = id&7 owns an 8x8 (nb,rb) quadrant (see header).
// wave w owns rows [32w, 32w+32) of the 128-row band; cols = 32 (2x16)
// ---------------------------------------------------------------------------
__global__ __launch_bounds__(256, 2) void tlstm_main(
    const unsigned short* __restrict__ xs,    // swizzled x tiles
    const unsigned short* __restrict__ hs,    // swizzled h0 tiles
    const unsigned short* __restrict__ ksw,   // swizzled kernel^T tiles
    const unsigned short* __restrict__ rsw,   // swizzled rk^T tiles
    const float* __restrict__ tvec,           // [4096]
    const float* __restrict__ c0,             // [4096][512]
    const float* __restrict__ ktime,          // [1536] cols [t1,t2,o]
    float* __restrict__ out)                  // h, then c_m
{
    // per buffer: A 8192 elems (16KB) + B 10240 elems (20KB) = 36KB; x2 = 72KB
    __shared__ __align__(16) unsigned short lds[2][18432];

    const int tid = threadIdx.x;
    const int wave = tid >> 6;
    const int lane = tid & 63;
    const int lr = lane & 15;
    const int lq = lane >> 4;

    // ---- XCD-aware block remap (bijective; 512 = 8 XCDs x 64 slots) ----
    // XCD k = id&7 gets nb in [8*(k&1), 8*(k&1)+8), rb in [8*(k>>1), 8*(k>>1)+8)
    // per-XCD L2 working set: 8 A-bands (1.5MB) + 8 B-col-tiles (1.4MB) < 4MB
    const int bid  = blockIdx.x;
    const int xcd  = bid & 7;
    const int slot = bid >> 3;
    const int nb   = (xcd & 1) * 8 + (slot & 7);
    const int rb   = (xcd >> 1) * 8 + (slot >> 3);

    f32x4_t acc[8][2][2];
#pragma unroll
    for (int m = 0; m < 8; ++m)
#pragma unroll
        for (int p = 0; p < 2; ++p)
#pragma unroll
            for (int n = 0; n < 2; ++n)
                acc[m][p][n] = (f32x4_t){0.f, 0.f, 0.f, 0.f};

    // ---- staging: linear global_load_lds, wave-uniform LDS dest ----
    auto stage = [&](int s, int buf) {
        unsigned short* ab = &lds[buf][0];
        unsigned short* bb = &lds[buf][8192];
        if (s < 4) {
            const unsigned short* at = xs + (size_t)(rb * 4 + s) * 8192;
#pragma unroll
            for (int j = 0; j < 4; ++j)
                gl16(at + (j * 256 + tid) * 8, ab + (j * 256 + wave * 64) * 8);
            const unsigned short* bt = ksw + (size_t)(nb * 4 + s) * 10240;
#pragma unroll
            for (int j = 0; j < 5; ++j)
                gl16(bt + (j * 256 + tid) * 8, bb + (j * 256 + wave * 64) * 8);
        } else {
            const unsigned short* at = hs + (size_t)(rb * 8 + (s - 4)) * 8192;
#pragma unroll
            for (int j = 0; j < 4; ++j)
                gl16(at + (j * 256 + tid) * 8, ab + (j * 256 + wave * 64) * 8);
            const unsigned short* bt = rsw + (size_t)(nb * 8 + (s - 4)) * 6144;
#pragma unroll
            for (int j = 0; j < 3; ++j)
                gl16(bt + (j * 256 + tid) * 8, bb + (j * 256 + wave * 64) * 8);
        }
    };

    auto compute1 = [&](int buf) {      // x @ kernel -> acc[0..4]
        const unsigned short* ab = &lds[buf][0];
        const unsigned short* bb = &lds[buf][8192];
#pragma unroll
        for (int ks = 0; ks < 2; ++ks) {
            const int kc = ks * 4 + lq;
            const int r0 = wave * 32 + lr;
            short8_t a0 = *reinterpret_cast<const short8_t*>(ab + SWZ(r0, kc));
            short8_t a1 = *reinterpret_cast<const short8_t*>(ab + SWZ(r0 + 16, kc));
#pragma unroll
            for (int m = 0; m < 5; ++m)
#pragma unroll
                for (int n = 0; n < 2; ++n) {
                    const int r = m * 32 + n * 16 + lr;
                    short8_t b = *reinterpret_cast<const short8_t*>(bb + SWZ(r, kc));
                    acc[m][0][n] = __builtin_amdgcn_mfma_f32_16x16x32_bf16(a0, b, acc[m][0][n], 0, 0, 0);
                    acc[m][1][n] = __builtin_amdgcn_mfma_f32_16x16x32_bf16(a1, b, acc[m][1][n], 0, 0, 0);
                }
        }
    };

    auto compute2 = [&](int buf) {      // h0 @ rk -> acc[5..7]
        const unsigned short* ab = &lds[buf][0];
        const unsigned short* bb = &lds[buf][8192];
#pragma unroll
        for (int ks = 0; ks < 2; ++ks) {
            const int kc = ks * 4 + lq;
            const int r0 = wave * 32 + lr;
            short8_t a0 = *reinterpret_cast<const short8_t*>(ab + SWZ(r0, kc));
            short8_t a1 = *reinterpret_cast<const short8_t*>(ab + SWZ(r0 + 16, kc));
#pragma unroll
            for (int m = 0; m < 3; ++m)
#pragma unroll
                for (int n = 0; n < 2; ++n) {
                    const int r = m * 32 + n * 16 + lr;
                    short8_t b = *reinterpret_cast<const short8_t*>(bb + SWZ(r, kc));
                    acc[5 + m][0][n] = __builtin_amdgcn_mfma_f32_16x16x32_bf16(a0, b, acc[5 + m][0][n], 0, 0, 0);
                    acc[5 + m][1][n] = __builtin_amdgcn_mfma_f32_16x16x32_bf16(a1, b, acc[5 + m][1][n], 0, 0, 0);
                }
        }
    };

    // ---- 2-phase pipelined K-loop: 12 steps (4 phase1 + 8 phase2) ----
    int cur = 0;
    stage(0, 0);
    __syncthreads();                    // drains vmcnt(0): tile 0 resident
#pragma unroll 1
    for (int s = 0; s < 12; ++s) {
        if (s < 11) stage(s + 1, cur ^ 1);   // prefetch in flight under compute
        if (s < 4) compute1(cur); else compute2(cur);
        __syncthreads();                // drains vmcnt+lgkm: next tile ready
        cur ^= 1;
    }

    // ---- epilogue: TimeLSTM elementwise (fp32) ----
    const float NEG_EPS = -1e-5f;
#pragma unroll
    for (int n = 0; n < 2; ++n) {
        const int u = nb * 32 + n * 16 + lr;
        const float kt1 = ktime[u];
        const float kt2 = ktime[U_N + u];
        const float kto = ktime[2 * U_N + u];
#pragma unroll
        for (int p = 0; p < 2; ++p)
#pragma unroll
            for (int i2 = 0; i2 < 4; ++i2) {
                const int b = rb * 128 + wave * 32 + p * 16 + lq * 4 + i2;
                const float tb = tvec[b];
                const float c0v = c0[(size_t)b * U_N + u];
                const float x_i  = acc[0][p][n][i2];
                const float x_c  = acc[1][p][n][i2];
                const float x_o  = acc[2][p][n][i2];
                const float x_t1 = acc[3][p][n][i2];
                const float x_t2 = acc[4][p][n][i2];
                const float r_i  = acc[5][p][n][i2];
                const float r_c  = acc[6][p][n][i2];
                const float r_o  = acc[7][p][n][i2];

                const float ig  = sigf(x_i + r_i);
                const float t1v = sigf(x_t1 + sigf(tb * kt1));
                const float t1c = (t1v > NEG_EPS) ? NEG_EPS : t1v;
                const float t2v = sigf(x_t2 + sigf(tb * kt2));
                const float ct  = tanhf(x_c + r_c);
                const float cm_ = (1.f - ig * t1v) * c0v + ig * ct * t1c;
                const float cm  = (1.f - ig) * c0v + ig * ct * t2v;
                const float og  = sigf(x_o + r_o + tb * kto);

                out[(size_t)b * U_N + u] = tanhf(cm_) * og;
                out[(size_t)B_N * U_N + (size_t)b * U_N + u] = cm;
            }
    }
}

// ---------------------------------------------------------------------------
extern "C" void kernel_launch(void* const* d_in, const int* in_sizes, int n_in,
                              void* d_out, int out_size, void* d_ws, size_t ws_size,
                              hipStream_t stream) {
    const float* x     = (const float*)d_in[0];   // [4096][256]
    const float* t     = (const float*)d_in[1];   // [4096][1]
    const float* h0    = (const float*)d_in[2];   // [4096][512]
    const float* c0    = (const float*)d_in[3];   // [4096][512]
    const float* kern  = (const float*)d_in[4];   // [256][2560]
    const float* rk    = (const float*)d_in[5];   // [512][1536]
    const float* ktime = (const float*)d_in[6];   // [1][1536]
    float* out = (float*)d_out;

    // ws layout (bytes):
    //   xs  @ 0        : 4096*256*2  = 2,097,152  (swizzled 128x64 tiles)
    //   hs  @ 2097152  : 4096*512*2  = 4,194,304
    //   ksw @ 6291456  : 2560*256*2  = 1,310,720  (swizzled 160x64 tiles)
    //   rsw @ 7602176  : 1536*512*2  = 1,572,864  (swizzled  96x64 tiles)
    unsigned short* xs  = (unsigned short*)d_ws;
    unsigned short* hs  = (unsigned short*)((char*)d_ws + 2097152);
    unsigned short* ksw = (unsigned short*)((char*)d_ws + 6291456);
    unsigned short* rsw = (unsigned short*)((char*)d_ws + 7602176);

    prep<<<2240, 256, 0, stream>>>(x, h0, kern, rk, xs, hs, ksw, rsw);
    tlstm_main<<<512, 256, 0, stream>>>(
        xs, hs, ksw, rsw, t, c0, ktime, out);
}

// Round 2
// 33.188 us; speedup vs baseline: 1.0510x; 1.0510x over previous
//
#include <hip/hip_runtime.h>

// ---------------------------------------------------------------------------
// TimeLSTMCell fused kernel for MI355X (gfx950) — round 4
// B=4096, D=256, U=512; out = concat(h, c_m) fp32
//
// prep kernel: converts x,h0 -> bf16 and kernel,rk -> transposed bf16, all
//   written as 128x64 (A) / {160,96}x64 (B) tiles with the LDS XOR-swizzle
//   PRE-BAKED into the tile layout, so the main kernel stages with linear
//   global_load_lds (wave-uniform dest + lane*16) and reads with the swizzle.
// main kernel: 128x32 output tile, 4 waves, BK=64, double-buffered LDS,
//   2-phase pipeline (STAGE next || COMPUTE cur || barrier), 12 K-steps
//   (4 for x@kernel K=256, 8 for h0@rk K=512), fused fp32 epilogue.
//
// ROUND 4 CHANGES (round-3 XCD remap was neutral -> reverted to plain grid):
//  1. Wave repartition 4x(32r x 32c) -> 2x2 grid of (64r x 16c). Each B
//     fragment now feeds 4 MFMAs (was 2): ds_read_b128 per phase1 K-step
//     drops 24->18 per wave (phase2 16->14). The LDS port (~12cyc/b128,
//     ~3150 cyc/CU/step incl. staging writes) was the binding resource vs
//     1552 cyc of MFMA; this cuts the read side ~25%.
//  2. tanhf (libm, branchy) -> 1 - 2/(1+__expf(2z)) in the epilogue tail.
// ---------------------------------------------------------------------------

typedef __attribute__((ext_vector_type(8))) short short8_t;   // 8 bf16
typedef __attribute__((ext_vector_type(4))) float f32x4_t;
typedef unsigned int u32;

#define B_N 4096
#define D_K 256
#define U_N 512

__device__ __forceinline__ unsigned short f2bf(float f) {
    unsigned int x = __float_as_uint(f);
    unsigned int r = x + 0x7fffu + ((x >> 16) & 1u);   // RNE
    return (unsigned short)(r >> 16);
}

__device__ __forceinline__ float sigf(float z) {
    return 1.0f / (1.0f + __expf(-z));
}

// fast tanh: exact at +/-inf (2/inf=0 -> 1; exp(-big)=0 -> -1), ~1e-7 abs err
__device__ __forceinline__ float tanhfast(float z) {
    return 1.0f - 2.0f / (1.0f + __expf(2.0f * z));
}

__device__ __forceinline__ void gl16(const unsigned short* g, unsigned short* l) {
    __builtin_amdgcn_global_load_lds(
        (const __attribute__((address_space(1))) u32*)g,
        (__attribute__((address_space(3))) u32*)l, 16, 0, 0);
}

// swizzled element offset of (row r, k-chunk kc) inside a tile with 8 chunks/row
#define SWZ(r, kc) ((((r) * 8) + ((kc) ^ ((r) & 7))) * 8)

// ---------------------------------------------------------------------------
// prepass: one kernel, 4 segments by flat chunk id (16B bf16 chunk each)
//   x  : 131072 chunks -> tiles (rb 0..31, kb 0..3)  of 128x64
//   h0 : 262144 chunks -> tiles (rb 0..31, kb 0..7)  of 128x64
//   ker:  81920 chunks -> tiles (nb 0..15, kb 0..3)  of 160x64 (transposed)
//   rk :  98304 chunks -> tiles (nb 0..15, kb 0..7)  of  96x64 (transposed)
// total 573440 chunks = 2240 blocks x 256
// ---------------------------------------------------------------------------
__global__ __launch_bounds__(256) void prep(
    const float* __restrict__ x, const float* __restrict__ h0,
    const float* __restrict__ kern, const float* __restrict__ rk,
    unsigned short* __restrict__ xs, unsigned short* __restrict__ hs,
    unsigned short* __restrict__ ksw, unsigned short* __restrict__ rsw)
{
    const int c = blockIdx.x * 256 + threadIdx.x;
    if (c < 131072) {                       // ---- x ----
        const int t = c >> 10, q = c & 1023;
        const int row = q >> 3, kc = q & 7;
        const int rb = t >> 2, kb = t & 3;
        const float* s = x + (size_t)(rb * 128 + row) * D_K + kb * 64 + kc * 8;
        short8_t o;
#pragma unroll
        for (int j = 0; j < 8; ++j) o[j] = (short)f2bf(s[j]);
        *reinterpret_cast<short8_t*>(xs + (size_t)t * 8192 + SWZ(row, kc)) = o;
    } else if (c < 393216) {                // ---- h0 ----
        const int c2 = c - 131072;
        const int t = c2 >> 10, q = c2 & 1023;
        const int row = q >> 3, kc = q & 7;
        const int rb = t >> 3, kb = t & 7;
        const float* s = h0 + (size_t)(rb * 128 + row) * U_N + kb * 64 + kc * 8;
        short8_t o;
#pragma unroll
        for (int j = 0; j < 8; ++j) o[j] = (short)f2bf(s[j]);
        *reinterpret_cast<short8_t*>(hs + (size_t)t * 8192 + SWZ(row, kc)) = o;
    } else if (c < 475136) {                // ---- kernel (transpose) ----
        const int c2 = c - 393216;
        const int t = c2 / 1280, q = c2 - t * 1280;
        const int kc = q / 160, r = q - kc * 160;     // r = mat*32 + cc
        const int nb = t >> 2, kb = t & 3;
        const int col = (r >> 5) * U_N + nb * 32 + (r & 31);
        short8_t o;
#pragma unroll
        for (int j = 0; j < 8; ++j)
            o[j] = (short)f2bf(kern[(size_t)(kb * 64 + kc * 8 + j) * 2560 + col]);
        *reinterpret_cast<short8_t*>(ksw + (size_t)t * 10240 + SWZ(r, kc)) = o;
    } else {                                // ---- rk (transpose) ----
        const int c2 = c - 475136;
        const int t = c2 / 768, q = c2 - t * 768;
        const int kc = q / 96, r = q - kc * 96;       // r = mat*32 + cc
        const int nb = t >> 3, kb = t & 7;
        const int col = (r >> 5) * U_N + nb * 32 + (r & 31);
        short8_t o;
#pragma unroll
        for (int j = 0; j < 8; ++j)
            o[j] = (short)f2bf(rk[(size_t)(kb * 64 + kc * 8 + j) * 1536 + col]);
        *reinterpret_cast<short8_t*>(rsw + (size_t)t * 6144 + SWZ(r, kc)) = o;
    }
}

// ---------------------------------------------------------------------------
// main fused kernel
// grid (16, 32) = 512 blocks (2/CU), 256 threads (4 waves)
// wave (wm,wn) = (wave>>1, wave&1) owns rows [64*wm, 64*wm+64) x cols
// [16*wn, 16*wn+16) of the 128x32 band, for every stacked gate matrix.
// ---------------------------------------------------------------------------
__global__ __launch_bounds__(256, 2) void tlstm_main(
    const unsigned short* __restrict__ xs,    // swizzled x tiles
    const unsigned short* __restrict__ hs,    // swizzled h0 tiles
    const unsigned short* __restrict__ ksw,   // swizzled kernel^T tiles
    const unsigned short* __restrict__ rsw,   // swizzled rk^T tiles
    const float* __restrict__ tvec,           // [4096]
    const float* __restrict__ c0,             // [4096][512]
    const float* __restrict__ ktime,          // [1536] cols [t1,t2,o]
    float* __restrict__ out)                  // h, then c_m
{
    // per buffer: A 8192 elems (16KB) + B 10240 elems (20KB) = 36KB; x2 = 72KB
    __shared__ __align__(16) unsigned short lds[2][18432];

    const int tid = threadIdx.x;
    const int wave = tid >> 6;
    const int lane = tid & 63;
    const int lr = lane & 15;
    const int lq = lane >> 4;
    const int wm = wave >> 1;                 // 0..1 : row half
    const int wn = wave & 1;                  // 0..1 : col half
    const int nb = blockIdx.x;
    const int rb = blockIdx.y;

    // acc[m][p]: gate matrix m (0..4 = x@K gates, 5..7 = h0@RK gates),
    // row-fragment p (rows wm*64 + p*16), cols wn*16..+16
    f32x4_t acc[8][4];
#pragma unroll
    for (int m = 0; m < 8; ++m)
#pragma unroll
        for (int p = 0; p < 4; ++p)
            acc[m][p] = (f32x4_t){0.f, 0.f, 0.f, 0.f};

    // ---- staging: linear global_load_lds, wave-uniform LDS dest ----
    auto stage = [&](int s, int buf) {
        unsigned short* ab = &lds[buf][0];
        unsigned short* bb = &lds[buf][8192];
        if (s < 4) {
            const unsigned short* at = xs + (size_t)(rb * 4 + s) * 8192;
#pragma unroll
            for (int j = 0; j < 4; ++j)
                gl16(at + (j * 256 + tid) * 8, ab + (j * 256 + wave * 64) * 8);
            const unsigned short* bt = ksw + (size_t)(nb * 4 + s) * 10240;
#pragma unroll
            for (int j = 0; j < 5; ++j)
                gl16(bt + (j * 256 + tid) * 8, bb + (j * 256 + wave * 64) * 8);
        } else {
            const unsigned short* at = hs + (size_t)(rb * 8 + (s - 4)) * 8192;
#pragma unroll
            for (int j = 0; j < 4; ++j)
                gl16(at + (j * 256 + tid) * 8, ab + (j * 256 + wave * 64) * 8);
            const unsigned short* bt = rsw + (size_t)(nb * 8 + (s - 4)) * 6144;
#pragma unroll
            for (int j = 0; j < 3; ++j)
                gl16(bt + (j * 256 + tid) * 8, bb + (j * 256 + wave * 64) * 8);
        }
    };

    auto compute1 = [&](int buf) {      // x @ kernel -> acc[0..4]
        const unsigned short* ab = &lds[buf][0];
        const unsigned short* bb = &lds[buf][8192];
#pragma unroll
        for (int ks = 0; ks < 2; ++ks) {
            const int kc = ks * 4 + lq;
            short8_t a[4];
#pragma unroll
            for (int p = 0; p < 4; ++p)
                a[p] = *reinterpret_cast<const short8_t*>(ab + SWZ(wm * 64 + p * 16 + lr, kc));
#pragma unroll
            for (int m = 0; m < 5; ++m) {
                const int r = m * 32 + wn * 16 + lr;
                short8_t b = *reinterpret_cast<const short8_t*>(bb + SWZ(r, kc));
#pragma unroll
                for (int p = 0; p < 4; ++p)
                    acc[m][p] = __builtin_amdgcn_mfma_f32_16x16x32_bf16(a[p], b, acc[m][p], 0, 0, 0);
            }
        }
    };

    auto compute2 = [&](int buf) {      // h0 @ rk -> acc[5..7]
        const unsigned short* ab = &lds[buf][0];
        const unsigned short* bb = &lds[buf][8192];
#pragma unroll
        for (int ks = 0; ks < 2; ++ks) {
            const int kc = ks * 4 + lq;
            short8_t a[4];
#pragma unroll
            for (int p = 0; p < 4; ++p)
                a[p] = *reinterpret_cast<const short8_t*>(ab + SWZ(wm * 64 + p * 16 + lr, kc));
#pragma unroll
            for (int m = 0; m < 3; ++m) {
                const int r = m * 32 + wn * 16 + lr;
                short8_t b = *reinterpret_cast<const short8_t*>(bb + SWZ(r, kc));
#pragma unroll
                for (int p = 0; p < 4; ++p)
                    acc[5 + m][p] = __builtin_amdgcn_mfma_f32_16x16x32_bf16(a[p], b, acc[5 + m][p], 0, 0, 0);
            }
        }
    };

    // ---- 2-phase pipelined K-loop: 12 steps (4 phase1 + 8 phase2) ----
    int cur = 0;
    stage(0, 0);
    __syncthreads();                    // drains vmcnt(0): tile 0 resident
#pragma unroll 1
    for (int s = 0; s < 12; ++s) {
        if (s < 11) stage(s + 1, cur ^ 1);   // prefetch in flight under compute
        if (s < 4) compute1(cur); else compute2(cur);
        __syncthreads();                // drains vmcnt+lgkm: next tile ready
        cur ^= 1;
    }

    // ---- epilogue: TimeLSTM elementwise (fp32) ----
    const float NEG_EPS = -1e-5f;
    const int u = nb * 32 + wn * 16 + lr;
    const float kt1 = ktime[u];
    const float kt2 = ktime[U_N + u];
    const float kto = ktime[2 * U_N + u];
#pragma unroll
    for (int p = 0; p < 4; ++p)
#pragma unroll
        for (int i2 = 0; i2 < 4; ++i2) {
            const int b = rb * 128 + wm * 64 + p * 16 + lq * 4 + i2;
            const float tb = tvec[b];
            const float c0v = c0[(size_t)b * U_N + u];
            const float x_i  = acc[0][p][i2];
            const float x_c  = acc[1][p][i2];
            const float x_o  = acc[2][p][i2];
            const float x_t1 = acc[3][p][i2];
            const float x_t2 = acc[4][p][i2];
            const float r_i  = acc[5][p][i2];
            const float r_c  = acc[6][p][i2];
            const float r_o  = acc[7][p][i2];

            const float ig  = sigf(x_i + r_i);
            const float t1v = sigf(x_t1 + sigf(tb * kt1));
            const float t1c = (t1v > NEG_EPS) ? NEG_EPS : t1v;
            const float t2v = sigf(x_t2 + sigf(tb * kt2));
            const float ct  = tanhfast(x_c + r_c);
            const float cm_ = (1.f - ig * t1v) * c0v + ig * ct * t1c;
            const float cm  = (1.f - ig) * c0v + ig * ct * t2v;
            const float og  = sigf(x_o + r_o + tb * kto);

            out[(size_t)b * U_N + u] = tanhfast(cm_) * og;
            out[(size_t)B_N * U_N + (size_t)b * U_N + u] = cm;
        }

}

// ---------------------------------------------------------------------------
extern "C" void kernel_launch(void* const* d_in, const int* in_sizes, int n_in,
                              void* d_out, int out_size, void* d_ws, size_t ws_size,
                              hipStream_t stream) {
    const float* x     = (const float*)d_in[0];   // [4096][256]
    const float* t     = (const float*)d_in[1];   // [4096][1]
    const float* h0    = (const float*)d_in[2];   // [4096][512]
    const float* c0    = (const float*)d_in[3];   // [4096][512]
    const float* kern  = (const float*)d_in[4];   // [256][2560]
    const float* rk    = (const float*)d_in[5];   // [512][1536]
    const float* ktime = (const float*)d_in[6];   // [1][1536]
    float* out = (float*)d_out;

    // ws layout (bytes):
    //   xs  @ 0        : 4096*256*2  = 2,097,152  (swizzled 128x64 tiles)
    //   hs  @ 2097152  : 4096*512*2  = 4,194,304
    //   ksw @ 6291456  : 2560*256*2  = 1,310,720  (swizzled 160x64 tiles)
    //   rsw @ 7602176  : 1536*512*2  = 1,572,864  (swizzled  96x64 tiles)
    unsigned short* xs  = (unsigned short*)d_ws;
    unsigned short* hs  = (unsigned short*)((char*)d_ws + 2097152);
    unsigned short* ksw = (unsigned short*)((char*)d_ws + 6291456);
    unsigned short* rsw = (unsigned short*)((char*)d_ws + 7602176);

    prep<<<2240, 256, 0, stream>>>(x, h0, kern, rk, xs, hs, ksw, rsw);
    tlstm_main<<<dim3(16, 32), 256, 0, stream>>>(
        xs, hs, ksw, rsw, t, c0, ktime, out);
}